// Round 12
// baseline (375.171 us; speedup 1.0000x reference)
//
#include <hip/hip_runtime.h>
#include <math.h>

#define HDIM 768
#define NG   192        // HDIM/4 float4 groups
#define LMAX 512

__device__ __forceinline__ float dot4(const float4 a, const float4 b) {
  return a.x * b.x + a.y * b.y + a.z * b.z + a.w * b.w;
}
__device__ __forceinline__ void fma4(float4& a, const float s, const float4 b) {
  a.x += s * b.x; a.y += s * b.y; a.z += s * b.z; a.w += s * b.w;
}
__device__ __forceinline__ void scale4(float4& a, const float s) {
  a.x *= s; a.y *= s; a.z *= s; a.w *= s;
}

// Wave64 sum via DPP (VALU pipe only).
__device__ __forceinline__ float wave_sum64(float x) {
  x += __int_as_float(__builtin_amdgcn_update_dpp(0, __float_as_int(x), 0xB1,  0xF, 0xF, true)); // quad_perm [1,0,3,2]
  x += __int_as_float(__builtin_amdgcn_update_dpp(0, __float_as_int(x), 0x4E,  0xF, 0xF, true)); // quad_perm [2,3,0,1]
  x += __int_as_float(__builtin_amdgcn_update_dpp(0, __float_as_int(x), 0x124, 0xF, 0xF, true)); // row_ror:4
  x += __int_as_float(__builtin_amdgcn_update_dpp(0, __float_as_int(x), 0x128, 0xF, 0xF, true)); // row_ror:8
  x += __int_as_float(__builtin_amdgcn_update_dpp(0, __float_as_int(x), 0x142, 0xF, 0xF, true)); // row_bcast15
  x += __int_as_float(__builtin_amdgcn_update_dpp(0, __float_as_int(x), 0x143, 0xF, 0xF, true)); // row_bcast31
  return __int_as_float(__builtin_amdgcn_readlane(__float_as_int(x), 63));
}

// ---------------- kernel 0: input-width detection (slot writes) ----------------
__global__ __launch_bounds__(256) void detect_slots(const unsigned* __restrict__ mask_w,
                                                    const unsigned* __restrict__ smap_w,
                                                    unsigned* __restrict__ slots,
                                                    int mask_words, int smap_words) {
  __shared__ unsigned red[2];
  const int b = blockIdx.x, tid = threadIdx.x;
  if (tid < 2) red[tid] = 0;
  __syncthreads();
  const int gtid = b * 256 + tid, gsz = gridDim.x * 256;
  unsigned acc = 0;
  for (int i = gtid; i < mask_words / 2; i += gsz) acc |= mask_w[2 * i + 1];
  unsigned acc2 = 0;
  for (int i = gtid; i < smap_words / 2; i += gsz) acc2 |= smap_w[2 * i + 1];
  if (acc)  atomicOr(&red[0], 1u);
  if (acc2) atomicOr(&red[1], 1u);
  __syncthreads();
  if (tid == 0) { slots[b] = red[0]; slots[64 + b] = red[1]; }
}

// ---------------- kernel 1: Wc = Wq^T * Wk, c0 = bq * Wk ----------------
__global__ __launch_bounds__(256) void prep_wc(const float* __restrict__ Wq,
                                               const float* __restrict__ Wk,
                                               const float* __restrict__ bq,
                                               float* __restrict__ Wc,
                                               float* __restrict__ c0, int H) {
  __shared__ float As[16][33];
  __shared__ float Bs[16][65];
  __shared__ float bqs[16];
  const int i0 = blockIdx.x * 32, j0 = blockIdx.y * 64;
  const int idx = threadIdx.x;
  const int li = idx & 31, lk = idx >> 5;
  const int lj = idx & 63, lk2 = idx >> 6;
  const int tc = idx & 15, tr = idx >> 4;
  float c[2][4] = {{0.f,0.f,0.f,0.f},{0.f,0.f,0.f,0.f}};
  float cb[4] = {0.f,0.f,0.f,0.f};
  const bool bias_lane = (blockIdx.x == 0) && (tr == 0);
  for (int o0 = 0; o0 < H; o0 += 16) {
    __syncthreads();
    As[lk][li]       = Wq[(size_t)(o0 + lk) * H + i0 + li];
    As[lk + 8][li]   = Wq[(size_t)(o0 + lk + 8) * H + i0 + li];
    Bs[lk2][lj]      = Wk[(size_t)(o0 + lk2) * H + j0 + lj];
    Bs[lk2 + 4][lj]  = Wk[(size_t)(o0 + lk2 + 4) * H + j0 + lj];
    Bs[lk2 + 8][lj]  = Wk[(size_t)(o0 + lk2 + 8) * H + j0 + lj];
    Bs[lk2 + 12][lj] = Wk[(size_t)(o0 + lk2 + 12) * H + j0 + lj];
    if (idx < 16) bqs[idx] = bq[o0 + idx];
    __syncthreads();
#pragma unroll
    for (int k = 0; k < 16; ++k) {
      const float a0 = As[k][tr * 2], a1 = As[k][tr * 2 + 1];
      const float b0 = Bs[k][tc * 4],     b1 = Bs[k][tc * 4 + 1];
      const float b2 = Bs[k][tc * 4 + 2], b3 = Bs[k][tc * 4 + 3];
      c[0][0] += a0 * b0; c[0][1] += a0 * b1; c[0][2] += a0 * b2; c[0][3] += a0 * b3;
      c[1][0] += a1 * b0; c[1][1] += a1 * b1; c[1][2] += a1 * b2; c[1][3] += a1 * b3;
      if (bias_lane) {
        const float bv = bqs[k];
        cb[0] += bv * b0; cb[1] += bv * b1; cb[2] += bv * b2; cb[3] += bv * b3;
      }
    }
  }
#pragma unroll
  for (int j = 0; j < 4; ++j) {
    Wc[(size_t)(i0 + tr * 2) * H + j0 + tc * 4 + j]     = c[0][j];
    Wc[(size_t)(i0 + tr * 2 + 1) * H + j0 + tc * 4 + j] = c[1][j];
  }
  if (bias_lane) {
#pragma unroll
    for (int j = 0; j < 4; ++j) c0[j0 + tc * 4 + j] = cb[j];
  }
}

// ---------------- kernel 2: fused mean -> GEMV -> scores/softmax/pool ----------------
// r11 + L3 alignment: pass 1 streams DESCENDING, pass 2 walks the compacted
// valid-row list ASCENDING (head region L3-hot). Mask staged at kernel top;
// compaction duplicated in all waves (nv in registers) so the first pass-2
// loads are issued BEFORE the GEMV.
__global__ __launch_bounds__(384) void fused(const float* __restrict__ hs,
                                             const unsigned* __restrict__ mask_w,
                                             const float* __restrict__ Wc,
                                             const float* __restrict__ c0,
                                             const unsigned* __restrict__ slots,
                                             float* __restrict__ pooled, int L) {
  __shared__ float4 red2[NG];
  __shared__ float4 meanv4[NG];
  __shared__ float4 vv4[NG];
  __shared__ float4 redv4[6][NG];
  __shared__ float mw[6], sw[6];
  __shared__ int   mrow[LMAX];
  __shared__ int   vidx[LMAX];
  __shared__ unsigned mfl;
  const int n = blockIdx.x, tid = threadIdx.x;
  const int w = tid >> 6, lane = tid & 63;

  if (tid == 0) mfl = 0u;
  __syncthreads();
  if (tid < 64 && slots[tid]) atomicOr(&mfl, 1u);
  __syncthreads();

  // ---- mask row staged FIRST (overlaps nothing downstream) ----
  const int mask_is_i32 = (mfl != 0);
  for (int tt = tid; tt < L; tt += 384) {
    const size_t idx = (size_t)n * L + tt;
    mrow[tt] = (int)(mask_is_i32 ? mask_w[idx] : mask_w[2 * idx]);
  }

  // ---- pass 1: mean over L, DESCENDING stream (tail->head) ----
  const int half = tid / NG, t = tid - half * NG;
  const float4* hb = reinterpret_cast<const float4*>(hs) + (size_t)n * L * NG;
  float ax = 0.f, ay = 0.f, az = 0.f, aw = 0.f;
  int l = half;
  for (; l + 16 <= L; l += 16) {
    float4 u[8];
#pragma unroll
    for (int i = 0; i < 8; ++i) u[i] = hb[(size_t)(L - 1 - (l + 2 * i)) * NG + t];
#pragma unroll
    for (int i = 0; i < 8; ++i) { ax += u[i].x; ay += u[i].y; az += u[i].z; aw += u[i].w; }
  }
  for (; l < L; l += 2) {
    float4 u = hb[(size_t)(L - 1 - l) * NG + t];
    ax += u.x; ay += u.y; az += u.z; aw += u.w;
  }
  if (half == 1) { float4 o; o.x = ax; o.y = ay; o.z = az; o.w = aw; red2[t] = o; }
  __syncthreads();   // red2 + mrow ready

  if (half == 0) {
    const float inv = 1.0f / (float)L;
    const float4 r = red2[t];
    float4 o;
    o.x = (ax + r.x) * inv; o.y = (ay + r.y) * inv;
    o.z = (az + r.z) * inv; o.w = (aw + r.w) * inv;
    meanv4[t] = o;
  }

  // ---- compaction of valid rows: ALL waves run it (identical results,
  //      benign same-value LDS writes) -> nv lives in a register per wave ----
  int nv = 0;
  for (int seg = 0; seg < L; seg += 64) {
    const int mv = mrow[seg + lane];
    const unsigned long long bal = __ballot(mv != 0);
    const int rank = __popcll(bal & ((1ull << lane) - 1ull));
    if (mv != 0) vidx[nv + rank] = seg + lane;
    nv += __popcll(bal);
  }

  // ---- pass-2 state + prefetch of first two batches (before GEMV) ----
  const int cntw = (nv > w) ? ((nv - 1 - w) / 6 + 1) : 0;
  float4 xa[2][3], xb[2][3];
  auto ld = [&](float4 (&X)[2][3], int j) {
#pragma unroll
    for (int u = 0; u < 2; ++u) {
      const int jj = j + u;
      const int rr = (jj < cntw) ? vidx[6 * jj + w] : vidx[0];
      const float4* rp = hb + (size_t)rr * NG;
      X[u][0] = rp[lane]; X[u][1] = rp[64 + lane]; X[u][2] = rp[128 + lane];
    }
  };
  if (nv > 0) { ld(xa, 0); ld(xb, 2); }   // in flight across the GEMV

  // ---- GEMV: v = mean * Wc + c0 ----
  __syncthreads();   // meanv4 ready
  {
    const int c1 = tid, c2 = tid + 384;
    float acc1 = 0.f, acc2 = 0.f;
    const float* wp = Wc;
    for (int o = 0; o < HDIM; o += 4) {
      const float4 mv = meanv4[o >> 2];
      acc1 += mv.x * wp[c1] + mv.y * wp[HDIM + c1] + mv.z * wp[2 * HDIM + c1] + mv.w * wp[3 * HDIM + c1];
      acc2 += mv.x * wp[c2] + mv.y * wp[HDIM + c2] + mv.z * wp[2 * HDIM + c2] + mv.w * wp[3 * HDIM + c2];
      wp += 4 * HDIM;
    }
    ((float*)vv4)[c1] = acc1 + c0[c1];
    ((float*)vv4)[c2] = acc2 + c0[c2];
  }
  __syncthreads();   // vv4 ready

  if (nv == 0) {
    // all rows masked: reference softmax is uniform -> pooled = mean
#pragma unroll
    for (int part = 0; part < 2; ++part) {
      const int col = part * 384 + tid;
      pooled[(size_t)n * HDIM + col] = ((const float*)meanv4)[col];
    }
    return;
  }

  // ---- pass 2: valid rows only (ascending = L3-hot head first) ----
  const float4 vf0 = vv4[lane], vf1 = vv4[64 + lane], vf2 = vv4[128 + lane];
  const float scale = 1.0f / sqrtf((float)HDIM);
  const int cmax = (nv + 5) / 6;
  const int jmax = (cmax + 3) & ~3;
  float m = -3.0e38f, ss = 0.f;
  float4 A0 = {0,0,0,0}, A1 = {0,0,0,0}, A2 = {0,0,0,0};

  auto pr = [&](float4 (&X)[2][3], int j) {
    float s[2];
#pragma unroll
    for (int u = 0; u < 2; ++u) {
      const float p = wave_sum64(dot4(X[u][0], vf0) + dot4(X[u][1], vf1) + dot4(X[u][2], vf2));
      s[u] = (j + u < cntw) ? p * scale : -3.0e38f;
    }
    const float mc = fmaxf(s[0], s[1]);
    if (mc > m) {   // defer-rescale (wave-uniform)
      const float f = __expf(m - mc);
      ss *= f; scale4(A0, f); scale4(A1, f); scale4(A2, f);
      m = mc;
    }
#pragma unroll
    for (int u = 0; u < 2; ++u) {
      const float pq = (j + u < cntw) ? __expf(s[u] - m) : 0.f;
      ss += pq;
      fma4(A0, pq, X[u][0]); fma4(A1, pq, X[u][1]); fma4(A2, pq, X[u][2]);
    }
  };

  for (int j = 0; j < jmax; j += 4) {
    pr(xa, j);
    if (j + 4 < jmax) ld(xa, j + 4);
    pr(xb, j + 2);
    if (j + 6 < jmax) ld(xb, j + 6);
  }

  // ---- 6-way split-softmax merge ----
  if (lane == 0) { mw[w] = m; sw[w] = ss; }
  redv4[w][lane]       = A0;
  redv4[w][64 + lane]  = A1;
  redv4[w][128 + lane] = A2;
  __syncthreads();
  float M = mw[0];
#pragma unroll
  for (int j = 1; j < 6; ++j) M = fmaxf(M, mw[j]);
  float f[6], S = 0.f;
#pragma unroll
  for (int j = 0; j < 6; ++j) { f[j] = __expf(mw[j] - M); S += sw[j] * f[j]; }
  const float invS = 1.0f / S;
  const float* redp = (const float*)redv4;
#pragma unroll
  for (int part = 0; part < 2; ++part) {
    const int col = part * 384 + tid;
    float o = 0.f;
#pragma unroll
    for (int j = 0; j < 6; ++j) o += redp[j * HDIM + col] * f[j];
    pooled[(size_t)n * HDIM + col] = o * invS;
  }
}

// ---------------- kernel 3: segment mean ----------------
__global__ __launch_bounds__(256) void segmean(const float* __restrict__ pooled,
                                               const void* __restrict__ smap,
                                               const unsigned* __restrict__ slots_s,
                                               float* __restrict__ out, int N) {
  __shared__ unsigned fsh;
  const int t = blockIdx.x, tid = threadIdx.x;
  const int col = blockIdx.y * 256 + tid;
  if (tid == 0) {
    unsigned f = 0;
    for (int i = 0; i < 64; ++i) f |= slots_s[i];
    fsh = f;
  }
  __syncthreads();
  const int smap_is_i32 = (fsh != 0);
  float a = 0.f;
  int cnt = 0;
  for (int i = 0; i < N; ++i) {
    const int s = smap_is_i32 ? ((const int*)smap)[i]
                              : (int)((const long long*)smap)[i];
    if (s == t) { a += pooled[(size_t)i * HDIM + col]; ++cnt; }
  }
  out[(size_t)t * HDIM + col] = a / (float)(cnt > 0 ? cnt : 1);
}

extern "C" void kernel_launch(void* const* d_in, const int* in_sizes, int n_in,
                              void* d_out, int out_size, void* d_ws, size_t ws_size,
                              hipStream_t stream) {
  const float*    hs     = (const float*)d_in[0];
  const unsigned* mask_w = (const unsigned*)d_in[1];
  const void*     smap   = d_in[2];
  const float*    Wq     = (const float*)d_in[3];
  const float*    bq     = (const float*)d_in[4];
  const float*    Wk     = (const float*)d_in[5];
  // d_in[6] = bk: dead (adds per-row constant to scores -> softmax-invariant)

  const int N = in_sizes[2];           // 512
  const int L = in_sizes[1] / N;       // 512
  const int H = in_sizes[4];           // 768 (== HDIM)
  const int T = out_size / H;          // 32

  float* Wc     = (float*)d_ws;                    // [H,H]
  float* c0     = Wc + (size_t)H * H;              // [H]
  float* pooled = c0 + H;                          // [N,H]
  unsigned* slots = (unsigned*)(pooled + (size_t)N * H);  // [128]
  (void)ws_size; (void)n_in;

  detect_slots<<<64, 256, 0, stream>>>(mask_w, (const unsigned*)smap, slots, N * L, N);
  prep_wc<<<dim3(H / 32, H / 64), 256, 0, stream>>>(Wq, Wk, bq, Wc, c0, H);
  fused<<<N, 384, 0, stream>>>(hs, mask_w, Wc, c0, slots, pooled, L);
  segmean<<<dim3(T, 3), 256, 0, stream>>>(pooled, smap, slots + 64, (float*)d_out, N);
}